// Round 3
// baseline (636909.033 us; speedup 1.0000x reference)
//
#include <hip/hip_runtime.h>
#include <hip/hip_cooperative_groups.h>
#include <hip/hip_bf16.h>
#include <math.h>
#include <stddef.h>

namespace cg = cooperative_groups;

#define B   32
#define TE  400
#define TD  800
#define ED  512
#define DD  80
#define LS  1024
#define G4  4096
#define UN  128
#define FLT 32
#define KW  31
#define NT  512
#define NB  256

// dynamic LDS floats: staging buffer 592*33
#define SCR_F 19536

// ws offsets (floats)
#define OFF_H0   0                       // [B*LS]
#define OFF_H1   (OFF_H0 + B*LS)         // [B*LS]
#define OFF_AL   (OFF_H1 + B*LS)         // [2][B*TE]
#define OFF_DEN  (OFF_AL + 2*B*TE)       // [TD*B]
#define OFF_PQP  (OFF_DEN + TD*B)        // [8][B][UN]
#define OFF_Z0   (OFF_PQP + 8*B*UN)      // [B*G4]
#define OFF_Z1   (OFF_Z0 + B*G4)         // [B*G4]
#define OFF_FLS  (OFF_Z1 + B*G4)         // [B*TE*FLT]
#define OFF_KEYS (OFF_FLS + B*TE*FLT)    // [B*TE*UN]
#define ZERO_F   OFF_PQP                 // zero [0, OFF_PQP)

__device__ __forceinline__ float fsig(float x){ return 1.f/(1.f+__expf(-x)); }
__device__ __forceinline__ float ftanh(float x){ return 1.f - 2.f/(__expf(2.f*x)+1.f); }

// keys = values @ Wm : [B, TE, UN]
__global__ void keys_kernel(const float* __restrict__ values, const float* __restrict__ Wm,
                            float* __restrict__ keys)
{
    int b  = blockIdx.x;
    int tg = blockIdx.y;
    int tid = threadIdx.x;    // 128
    __shared__ __align__(16) float v[8*ED];
    const float* vb = values + (size_t)b*TE*ED + (size_t)tg*8*ED;
    for (int i = tid; i < 8*ED; i += 128) v[i] = vb[i];
    __syncthreads();
    int u = tid;
    float acc[8];
#pragma unroll
    for (int i=0;i<8;i++) acc[i]=0.f;
    for (int k=0;k<ED;k++){
        float w = Wm[k*UN + u];
#pragma unroll
        for (int tt=0; tt<8; tt++) acc[tt] += v[tt*ED + k]*w;
    }
#pragma unroll
    for (int tt=0; tt<8; tt++)
        keys[(size_t)b*TE*UN + (size_t)(tg*8+tt)*UN + u] = acc[tt];
}

// GEMM inner: thread (b_,kq) accumulates 16 contiguous cols (n0..n0+15) over its
// row slice. Weights read 64B-contiguous per row, broadcast across 32 b_ lanes.
__device__ __forceinline__ void gemm_rows(const float* __restrict__ xs,
                                          const float* __restrict__ wbase,
                                          int rpt, int kq, int b_, int n0,
                                          float4 acc[4])
{
    const float* xp = xs + (kq*rpt)*33 + b_;
    const float* wp = wbase + (size_t)(kq*rpt)*G4 + n0;
    for (int k = 0; k < rpt; k++){
        float xv = xp[(size_t)k*33];
        float4 w0 = *(const float4*)(wp + 0);
        float4 w1 = *(const float4*)(wp + 4);
        float4 w2 = *(const float4*)(wp + 8);
        float4 w3 = *(const float4*)(wp + 12);
        acc[0].x += xv*w0.x; acc[0].y += xv*w0.y; acc[0].z += xv*w0.z; acc[0].w += xv*w0.w;
        acc[1].x += xv*w1.x; acc[1].y += xv*w1.y; acc[1].z += xv*w1.z; acc[1].w += xv*w1.w;
        acc[2].x += xv*w2.x; acc[2].y += xv*w2.y; acc[2].z += xv*w2.z; acc[2].w += xv*w2.w;
        acc[3].x += xv*w3.x; acc[3].y += xv*w3.y; acc[3].z += xv*w3.z; acc[3].w += xv*w3.w;
        wp += G4;
    }
}

__device__ __forceinline__ void reduce_write_z(float* sc, const float4 acc[4],
                                               int kq, int b_, int tid, int n0,
                                               float* __restrict__ z)
{
#pragma unroll
    for (int g=0; g<4; g++){
        sc[kq*544 + b_*17 + g*4 + 0] = acc[g].x;
        sc[kq*544 + b_*17 + g*4 + 1] = acc[g].y;
        sc[kq*544 + b_*17 + g*4 + 2] = acc[g].z;
        sc[kq*544 + b_*17 + g*4 + 3] = acc[g].w;
    }
    __syncthreads();
    int b = tid >> 4, c = tid & 15;
    float s = 0.f;
#pragma unroll
    for (int q=0; q<16; q++) s += sc[q*544 + b*17 + c];
    z[(size_t)b*G4 + n0 + c] = s;
}

__launch_bounds__(NT, 1)
__global__ void persist(const float* __restrict__ enc, const float* __restrict__ dec,
                        const float* __restrict__ Wq,
                        const float* __restrict__ convk, const float* __restrict__ convb,
                        const float* __restrict__ Wloc,
                        const float* __restrict__ v_a, const float* __restrict__ b_a,
                        const float* __restrict__ W0, const float* __restrict__ U0,
                        const float* __restrict__ b0,
                        const float* __restrict__ W1, const float* __restrict__ U1,
                        const float* __restrict__ b1,
                        float* __restrict__ c_out, float* __restrict__ e_out,
                        float* __restrict__ ws)
{
    cg::grid_group grid = cg::this_grid();
    extern __shared__ float sc[];
    __shared__ float wlocs[FLT*UN];
    __shared__ float cks[KW*FLT];
    __shared__ float ckb[FLT];
    __shared__ float vas[UN];
    __shared__ float c0s[128];
    __shared__ float c1s[128];
    __shared__ float h1loc[128];
    __shared__ float invdp[B];
    __shared__ float aw[80];

    const int r   = blockIdx.x;
    const int tid = threadIdx.x;

    float* h0g    = ws + OFF_H0;
    float* h1g    = ws + OFF_H1;
    float* albuf  = ws + OFF_AL;
    float* denoms = ws + OFF_DEN;
    float* pqpart = ws + OFF_PQP;
    float* zbuf0  = ws + OFF_Z0;
    float* zbuf1  = ws + OFF_Z1;
    float* flsbuf = ws + OFF_FLS;
    float* keys   = ws + OFF_KEYS;

    for (int i = tid; i < FLT*UN; i += NT) wlocs[i] = Wloc[i];
    for (int i = tid; i < KW*FLT; i += NT) cks[i] = convk[i];
    if (tid < FLT) ckb[tid] = convb[tid];
    if (tid < UN)  vas[tid] = v_a[tid];
    if (tid < 128){ c0s[tid] = 0.f; c1s[tid] = 0.f; }
    __syncthreads();

    // XCD-aware column ownership: x = r&7 (assumed XCD), s = r>>3
    // gate gg = s&3, group ug = x*8 + (s>>2)  -> per XCD: 128 contiguous cols/gate
    const int xg = r & 7, sg = r >> 3;
    const int n0 = (sg & 3)*1024 + (xg*8 + (sg >> 2))*16;
    const int b_ = tid & 31;
    const int kq = tid >> 5;       // 0..15
    const int gb = r >> 3;         // gate/conv/energy batch
    const int j0 = (r & 7)*128;    // gate cell slice / conv seg id reuse

    for (int t = 0; t < TD; t++){
        if (tid < B) invdp[tid] = (t==0) ? 0.f : 1.f/denoms[(t-1)*B + tid];
        __syncthreads();

        // ===== P1: z0 = [dec_t, ctx_{t-1}, h0old] @ [W0;U0] ; z1a = h1old @ U1 =====
        float4 a0[4], a1[4];
#pragma unroll
        for (int g=0; g<4; g++){
            a0[g].x=0.f;a0[g].y=0.f;a0[g].z=0.f;a0[g].w=0.f;
            a1[g].x=0.f;a1[g].y=0.f;a1[g].z=0.f;a1[g].w=0.f;
        }
        // chunk 0: k 0..591 (dec + ctx)
        for (int j = 0; j < B; j++){
            const float* dsrc = dec + ((size_t)j*TD + t)*DD;
            const float* csrc = c_out + ((size_t)j*TD + (t>0?t-1:0))*ED;
            float iv = invdp[j];
            for (int k = tid; k < 592; k += NT){
                float v = (k < DD) ? dsrc[k] : ((t==0) ? 0.f : csrc[k-DD]*iv);
                sc[k*33 + j] = v;
            }
        }
        __syncthreads();
        gemm_rows(sc, W0, 37, kq, b_, n0, a0);
        __syncthreads();
        // chunks 1/2: h0old
        for (int half = 0; half < 2; half++){
            for (int j = 0; j < B; j++)
                sc[tid*33 + j] = h0g[(size_t)j*LS + half*512 + tid];
            __syncthreads();
            gemm_rows(sc, U0 + (size_t)half*512*G4, 32, kq, b_, n0, a0);
            __syncthreads();
        }
        // z1a: h1old @ U1
        for (int half = 0; half < 2; half++){
            for (int j = 0; j < B; j++)
                sc[tid*33 + j] = h1g[(size_t)j*LS + half*512 + tid];
            __syncthreads();
            gemm_rows(sc, U1 + (size_t)half*512*G4, 32, kq, b_, n0, a1);
            __syncthreads();
        }
        reduce_write_z(sc, a0, kq, b_, tid, n0, zbuf0);
        grid.sync();

        // ===== P2: gate0 -> h0new ; conv(align) =====
        if (tid < 128){
            int j = j0 + tid;
            float zi = zbuf0[(size_t)gb*G4 + j]        + b0[j];
            float zf = zbuf0[(size_t)gb*G4 + 1024 + j] + b0[1024 + j];
            float zg = zbuf0[(size_t)gb*G4 + 2048 + j] + b0[2048 + j];
            float zo = zbuf0[(size_t)gb*G4 + 3072 + j] + b0[3072 + j];
            float cn = fsig(zf)*c0s[tid] + fsig(zi)*ftanh(zg);
            c0s[tid] = cn;
            h0g[(size_t)gb*LS + j] = fsig(zo)*ftanh(cn);
        }
        {
            int p0 = (r & 7)*50;
            const float* alsrc = albuf + ((t&1)^1)*(B*TE) + gb*TE;
            float* aldst       = albuf + (t&1)*(B*TE) + gb*TE;
            const float* erow  = e_out + ((size_t)gb*TD + (t>0?t-1:0))*TE;
            float iv = invdp[gb];
            if (tid < 80){
                int p = p0 - 15 + tid;
                float v = 0.f;
                if (p >= 0 && p < TE)
                    v = alsrc[p] + ((t==0) ? 0.f : erow[p]*iv);
                aw[tid] = v;
                if (tid >= 15 && tid < 65) aldst[p] = v;
            }
            __syncthreads();
            for (int o = tid; o < 50*FLT; o += NT){
                int pos = o >> 5, f = o & 31;
                float s2 = ckb[f];
#pragma unroll
                for (int q=0; q<KW; q++) s2 += aw[pos+q]*cks[q*FLT + f];
                flsbuf[((size_t)gb*TE + p0 + pos)*FLT + f] = s2;
            }
        }
        grid.sync();

        // ===== P3: z1 = z1a + h0new @ W1 =====
        for (int half = 0; half < 2; half++){
            for (int j = 0; j < B; j++)
                sc[tid*33 + j] = h0g[(size_t)j*LS + half*512 + tid];
            __syncthreads();
            gemm_rows(sc, W1 + (size_t)half*512*G4, 32, kq, b_, n0, a1);
            __syncthreads();
        }
        reduce_write_z(sc, a1, kq, b_, tid, n0, zbuf1);
        grid.sync();

        // ===== P4: gate1 -> h1new ; pq partials =====
        if (tid < 128){
            int j = j0 + tid;
            float zi = zbuf1[(size_t)gb*G4 + j]        + b1[j];
            float zf = zbuf1[(size_t)gb*G4 + 1024 + j] + b1[1024 + j];
            float zg = zbuf1[(size_t)gb*G4 + 2048 + j] + b1[2048 + j];
            float zo = zbuf1[(size_t)gb*G4 + 3072 + j] + b1[3072 + j];
            float cn = fsig(zf)*c1s[tid] + fsig(zi)*ftanh(zg);
            c1s[tid] = cn;
            float hn = fsig(zo)*ftanh(cn);
            h1loc[tid] = hn;
            h1g[(size_t)gb*LS + j] = hn;
        }
        __syncthreads();
        {
            int u = tid & 127, ks = tid >> 7;   // 4 slices of 32 j
            const float* wq = Wq + (size_t)(j0 + ks*32)*UN + u;
            float s = 0.f;
#pragma unroll 8
            for (int jj = 0; jj < 32; jj++) s += h1loc[ks*32 + jj]*wq[(size_t)jj*UN];
            sc[ks*132 + u] = s;
        }
        __syncthreads();
        if (tid < 128){
            float s = sc[tid] + sc[132 + tid] + sc[264 + tid] + sc[396 + tid];
            pqpart[((size_t)(r&7)*B + gb)*UN + tid] = s;
        }
        grid.sync();

        // ===== P5: energy + denom + context partial =====
        {
            int t0c = (r & 7)*50;
            float* pqL  = sc;            // 128
            float* flsL = sc + 128;      // 1600
            float* elds = sc + 1728;     // 50*129
            float* esum = sc + 8178;     // 50
            if (tid < UN){
                float s = b_a[tid];
#pragma unroll
                for (int q=0; q<8; q++) s += pqpart[((size_t)q*B + gb)*UN + tid];
                pqL[tid] = s;
            }
            for (int i = tid; i < 50*FLT; i += NT)
                flsL[i] = flsbuf[((size_t)gb*TE + t0c)*FLT + i];
            __syncthreads();
            const float* kb = keys + ((size_t)gb*TE + t0c)*UN;
            for (int o = tid; o < 50*UN; o += NT){
                int pos = o >> 7, u = o & 127;
                float loc = 0.f;
                const float* fr = flsL + pos*FLT;
#pragma unroll
                for (int f=0; f<FLT; f++) loc += fr[f]*wlocs[f*UN + u];
                float x = kb[(size_t)pos*UN + u] + pqL[u] + loc;
                elds[pos*129 + u] = vas[u]*ftanh(x);
            }
            __syncthreads();
            if (tid < 50){
                float e = 0.f;
                for (int uu=0; uu<UN; uu++) e += elds[tid*129 + uu];
                float ex = __expf(e);    // |e| <= sum|v_a| ~ 5: max-free softmax safe
                e_out[((size_t)gb*TD + t)*TE + t0c + tid] = ex;
                esum[tid] = ex;
            }
            __syncthreads();
            if (tid == 0){
                float s = 0.f;
                for (int p=0; p<50; p++) s += esum[p];
                atomicAdd(&denoms[t*B + gb], s);
            }
            {
                float a = 0.f;
                const float* vb = enc + ((size_t)gb*TE + t0c)*ED + tid;
#pragma unroll 10
                for (int p=0; p<50; p++) a += esum[p]*vb[(size_t)p*ED];
                atomicAdd(&c_out[((size_t)gb*TD + t)*ED + tid], a);
            }
        }
        grid.sync();
    }
}

__global__ void epilogue(const float* __restrict__ denoms,
                         float* __restrict__ c_out, float* __restrict__ e_out)
{
    int blk = blockIdx.x;
    int bb = blk / TD, tt = blk - bb*TD;
    float invd = 1.f / denoms[tt*B + bb];
    float* cr = c_out + ((size_t)bb*TD + tt)*ED;
    float* er = e_out + ((size_t)bb*TD + tt)*TE;
    for (int d = threadIdx.x; d < ED; d += 256) cr[d] *= invd;
    for (int p = threadIdx.x; p < TE; p += 256) er[p] *= invd;
}

extern "C" void kernel_launch(void* const* d_in, const int* in_sizes, int n_in,
                              void* d_out, int out_size, void* d_ws, size_t ws_size,
                              hipStream_t stream)
{
    const float* enc   = (const float*)d_in[0];
    const float* dec   = (const float*)d_in[1];
    const float* Wm    = (const float*)d_in[2];
    const float* Wq    = (const float*)d_in[3];
    const float* convk = (const float*)d_in[4];
    const float* convb = (const float*)d_in[5];
    const float* Wloc  = (const float*)d_in[6];
    const float* v_a   = (const float*)d_in[7];
    const float* b_a   = (const float*)d_in[8];
    const float* W0    = (const float*)d_in[9];
    const float* U0    = (const float*)d_in[10];
    const float* b0    = (const float*)d_in[11];
    const float* W1    = (const float*)d_in[12];
    const float* U1    = (const float*)d_in[13];
    const float* b1    = (const float*)d_in[14];

    float* out    = (float*)d_out;
    float* c_outp = out;
    float* e_outp = out + (size_t)B*TD*ED;
    float* wsp    = (float*)d_ws;

    hipMemsetAsync(wsp, 0, (size_t)ZERO_F*sizeof(float), stream);
    hipMemsetAsync(c_outp, 0, (size_t)B*TD*ED*sizeof(float), stream);

    keys_kernel<<<dim3(B,50), 128, 0, stream>>>(enc, Wm, wsp + OFF_KEYS);

    hipFuncSetAttribute((const void*)persist,
                        hipFuncAttributeMaxDynamicSharedMemorySize, SCR_F*4);
    void* args[] = { (void*)&enc, (void*)&dec, (void*)&Wq, (void*)&convk, (void*)&convb,
                     (void*)&Wloc, (void*)&v_a, (void*)&b_a, (void*)&W0, (void*)&U0,
                     (void*)&b0, (void*)&W1, (void*)&U1, (void*)&b1,
                     (void*)&c_outp, (void*)&e_outp, (void*)&wsp };
    hipLaunchCooperativeKernel((void*)persist, dim3(NB), dim3(NT), args,
                               SCR_F*4, stream);

    epilogue<<<B*TD, 256, 0, stream>>>(wsp + OFF_DEN, c_outp, e_outp);
}